// Round 1
// baseline (13704.227 us; speedup 1.0000x reference)
//
#include <hip/hip_runtime.h>
#include <math.h>

#define LAYERS 2
#define HIDDEN 512
#define FFN_DIM 2048
#define HEADS 8
#define SLEN 2048
#define BSZ 2
#define KEY_DIM 64
#define V_DIM 1024
#define HEAD_SIZE 128
#define MROWS (BSZ * SLEN)          // 4096 rows
#define SCALE_BASE 512.0f
#define ATT_SCALING 0.125f          // KEY_DIM^-0.5
#define LN_EPS 1e-5f

// ---------------------------------------------------------------------------
// Tiled fp32 GEMM: C[M,N] = A[M,K] @ W[K,N] (+bias) (+relu)
// 64x64 output tile per 256-thread block, 4x4 register blocking.
// All M,N,K are multiples of 64/16 in this problem: no bounds checks.
// ---------------------------------------------------------------------------
template <int BIAS, int RELU>
__global__ __launch_bounds__(256) void gemm64(const float* __restrict__ A,
                                              const float* __restrict__ W,
                                              const float* __restrict__ bias,
                                              float* __restrict__ C,
                                              int M, int N, int K) {
    __shared__ float As[16][65];   // [k][m], padded to dodge store conflicts
    __shared__ float Bs[16][64];   // [k][n]

    const int tid = threadIdx.x;
    const int tx = tid & 15;       // 0..15 -> N direction
    const int ty = tid >> 4;       // 0..15 -> M direction
    const int row0 = blockIdx.y * 64 + ty * 4;
    const int col0 = blockIdx.x * 64 + tx * 4;

    float acc[4][4] = {};

    for (int kt = 0; kt < K; kt += 16) {
#pragma unroll
        for (int i = 0; i < 4; i++) {
            int e = tid + i * 256;       // 0..1023
            int m = e >> 4;              // 0..63
            int k = e & 15;              // 0..15
            As[k][m] = A[(size_t)(blockIdx.y * 64 + m) * K + kt + k];
        }
#pragma unroll
        for (int i = 0; i < 4; i++) {
            int e = tid + i * 256;
            int k = e >> 6;              // 0..15
            int n = e & 63;              // 0..63
            Bs[k][n] = W[(size_t)(kt + k) * N + blockIdx.x * 64 + n];
        }
        __syncthreads();
#pragma unroll
        for (int kk = 0; kk < 16; kk++) {
            float a[4], b[4];
#pragma unroll
            for (int i = 0; i < 4; i++) a[i] = As[kk][ty * 4 + i];
#pragma unroll
            for (int j = 0; j < 4; j++) b[j] = Bs[kk][tx * 4 + j];
#pragma unroll
            for (int i = 0; i < 4; i++)
#pragma unroll
                for (int j = 0; j < 4; j++) acc[i][j] += a[i] * b[j];
        }
        __syncthreads();
    }

#pragma unroll
    for (int i = 0; i < 4; i++) {
#pragma unroll
        for (int j = 0; j < 4; j++) {
            float v = acc[i][j];
            if (BIAS) v += bias[col0 + j];
            if (RELU) v = fmaxf(v, 0.0f);
            C[(size_t)(row0 + i) * N + col0 + j] = v;
        }
    }
}

// ---------------------------------------------------------------------------
// xPos rotary embedding applied in-place to Q and K.
// One thread per (b, s, h, j) rotary pair; j in [0,32).
// ---------------------------------------------------------------------------
__global__ __launch_bounds__(256) void xpos_kernel(float* __restrict__ Q,
                                                   float* __restrict__ K) {
    int idx = blockIdx.x * 256 + threadIdx.x;   // total BSZ*SLEN*HEADS*32 = 2^20
    int j = idx & 31;
    int h = (idx >> 5) & 7;
    int s = (idx >> 8) & (SLEN - 1);
    int b = idx >> 19;

    float base = (2.0f * j + 0.4f * KEY_DIM) / (1.4f * KEY_DIM);
    float pos = (float)(s - SLEN / 2);
    float scale = powf(base, pos / SCALE_BASE);
    float inv_freq = powf(10000.0f, -(float)j / 32.0f);
    float ang = (float)s * inv_freq;
    float sn = sinf(ang) * scale;
    float cs = cosf(ang) * scale;

    size_t off = ((size_t)(b * SLEN + s)) * HIDDEN + h * KEY_DIM + 2 * j;

    float q0 = Q[off], q1 = Q[off + 1];
    Q[off]     = q0 * cs - q1 * sn;
    Q[off + 1] = q1 * cs + q0 * sn;

    float k0 = K[off], k1 = K[off + 1];
    K[off]     = k0 * cs - k1 * sn;
    K[off + 1] = k1 * cs + k0 * sn;
}

// ---------------------------------------------------------------------------
// Attention: one block per (b, h, q-row). Scores in LDS, two-pass softmax,
// then PV with coalesced V reads. SCALING applied post-softmax (per ref).
// ---------------------------------------------------------------------------
__global__ __launch_bounds__(256) void attn_kernel(const float* __restrict__ Q,
                                                   const float* __restrict__ Kt,
                                                   const float* __restrict__ V,
                                                   float* __restrict__ O) {
    const int qrow = blockIdx.x;
    const int h = blockIdx.y;
    const int b = blockIdx.z;
    const int tid = threadIdx.x;

    __shared__ float qv[KEY_DIM];
    __shared__ float sc[SLEN];
    __shared__ float red[256];

    const float* qptr = Q + ((size_t)(b * SLEN + qrow)) * HIDDEN + h * KEY_DIM;
    if (tid < KEY_DIM) qv[tid] = qptr[tid];
    __syncthreads();

    // scores q . k
    for (int k = tid; k < SLEN; k += 256) {
        const float* kp = Kt + ((size_t)(b * SLEN + k)) * HIDDEN + h * KEY_DIM;
        float d = 0.0f;
#pragma unroll
        for (int i = 0; i < KEY_DIM; i++) d += qv[i] * kp[i];
        sc[k] = d;
    }
    __syncthreads();

    // block max
    float lm = -1e30f;
    for (int k = tid; k < SLEN; k += 256) lm = fmaxf(lm, sc[k]);
    red[tid] = lm;
    __syncthreads();
    for (int s = 128; s > 0; s >>= 1) {
        if (tid < s) red[tid] = fmaxf(red[tid], red[tid + s]);
        __syncthreads();
    }
    float m = red[0];
    __syncthreads();

    // exp + sum
    float ls = 0.0f;
    for (int k = tid; k < SLEN; k += 256) {
        float e = expf(sc[k] - m);
        sc[k] = e;
        ls += e;
    }
    red[tid] = ls;
    __syncthreads();
    for (int s = 128; s > 0; s >>= 1) {
        if (tid < s) red[tid] += red[tid + s];
        __syncthreads();
    }
    float inv = ATT_SCALING / red[0];
    __syncthreads();   // everyone has read red[0] before red is reused

    // PV: thread t handles dim = t&127, keys congruent to t>>7 (mod 2)
    const int dim = tid & 127;
    const int half = tid >> 7;
    float acc = 0.0f;
    const float* vbase = V + ((size_t)b * SLEN) * V_DIM + h * HEAD_SIZE + dim;
    for (int k = half; k < SLEN; k += 2) acc += sc[k] * vbase[(size_t)k * V_DIM];
    red[tid] = acc;
    __syncthreads();
    if (tid < 128) {
        O[((size_t)(b * SLEN + qrow)) * V_DIM + h * HEAD_SIZE + dim] =
            (red[tid] + red[tid + 128]) * inv;
    }
}

// ---------------------------------------------------------------------------
// y = LayerNorm(X + R) * g + be    (one block per row of 512)
// ---------------------------------------------------------------------------
__global__ __launch_bounds__(256) void addln_kernel(const float* __restrict__ X,
                                                    const float* __restrict__ R,
                                                    const float* __restrict__ g,
                                                    const float* __restrict__ be,
                                                    float* __restrict__ O) {
    const int row = blockIdx.x;
    const int tid = threadIdx.x;
    __shared__ float red[256];

    size_t off = (size_t)row * HIDDEN;
    float v0 = X[off + tid] + R[off + tid];
    float v1 = X[off + tid + 256] + R[off + tid + 256];

    red[tid] = v0 + v1;
    __syncthreads();
    for (int s = 128; s > 0; s >>= 1) {
        if (tid < s) red[tid] += red[tid + s];
        __syncthreads();
    }
    float mu = red[0] * (1.0f / HIDDEN);
    __syncthreads();

    float d0 = v0 - mu, d1 = v1 - mu;
    red[tid] = d0 * d0 + d1 * d1;
    __syncthreads();
    for (int s = 128; s > 0; s >>= 1) {
        if (tid < s) red[tid] += red[tid + s];
        __syncthreads();
    }
    float rstd = rsqrtf(red[0] * (1.0f / HIDDEN) + LN_EPS);

    O[off + tid]       = d0 * rstd * g[tid] + be[tid];
    O[off + tid + 256] = d1 * rstd * g[tid + 256] + be[tid + 256];
}

// ---------------------------------------------------------------------------
extern "C" void kernel_launch(void* const* d_in, const int* in_sizes, int n_in,
                              void* d_out, int out_size, void* d_ws, size_t ws_size,
                              hipStream_t stream) {
    const float* x   = (const float*)d_in[0];
    const float* Wq  = (const float*)d_in[1];
    const float* Wk  = (const float*)d_in[2];
    const float* Wv  = (const float*)d_in[3];
    const float* Wo  = (const float*)d_in[4];
    const float* W1  = (const float*)d_in[5];
    const float* b1  = (const float*)d_in[6];
    const float* W2  = (const float*)d_in[7];
    const float* b2  = (const float*)d_in[8];
    const float* g1  = (const float*)d_in[9];
    const float* be1 = (const float*)d_in[10];
    const float* g2  = (const float*)d_in[11];
    const float* be2 = (const float*)d_in[12];
    float* out = (float*)d_out;

    const size_t M1 = 1024 * 1024;   // in floats
    float* ws = (float*)d_ws;
    float* A  = ws;                  // 2M floats : current x
    float* Y  = ws + 2 * M1;         // 2M : post-attn LN output
    float* Qb = ws + 4 * M1;         // 2M
    float* Kb = ws + 6 * M1;         // 2M
    float* Vb = ws + 8 * M1;         // 4M
    float* AT = ws + 12 * M1;        // 4M : attention out (B,S,V_DIM)
    float* P  = Kb;                  // 2M : attn projection (K dead by then)
    float* F1 = Qb;                  // 8M : FFN hidden (Q/K/V dead by then)
    float* F2 = AT;                  // 2M : FFN out (AT dead by then)

    // A = x
    hipMemcpyAsync(A, x, (size_t)MROWS * HIDDEN * sizeof(float),
                   hipMemcpyDeviceToDevice, stream);

    for (int l = 0; l < LAYERS; l++) {
        const float* Wq_l  = Wq + (size_t)l * HIDDEN * HIDDEN;
        const float* Wk_l  = Wk + (size_t)l * HIDDEN * HIDDEN;
        const float* Wv_l  = Wv + (size_t)l * HIDDEN * V_DIM;
        const float* Wo_l  = Wo + (size_t)l * V_DIM * HIDDEN;
        const float* W1_l  = W1 + (size_t)l * HIDDEN * FFN_DIM;
        const float* b1_l  = b1 + (size_t)l * FFN_DIM;
        const float* W2_l  = W2 + (size_t)l * FFN_DIM * HIDDEN;
        const float* b2_l  = b2 + (size_t)l * HIDDEN;
        const float* g1_l  = g1 + (size_t)l * HIDDEN;
        const float* be1_l = be1 + (size_t)l * HIDDEN;
        const float* g2_l  = g2 + (size_t)l * HIDDEN;
        const float* be2_l = be2 + (size_t)l * HIDDEN;

        // Q, K, V projections
        gemm64<0, 0><<<dim3(HIDDEN / 64, MROWS / 64), 256, 0, stream>>>(
            A, Wq_l, nullptr, Qb, MROWS, HIDDEN, HIDDEN);
        gemm64<0, 0><<<dim3(HIDDEN / 64, MROWS / 64), 256, 0, stream>>>(
            A, Wk_l, nullptr, Kb, MROWS, HIDDEN, HIDDEN);
        gemm64<0, 0><<<dim3(V_DIM / 64, MROWS / 64), 256, 0, stream>>>(
            A, Wv_l, nullptr, Vb, MROWS, V_DIM, HIDDEN);

        // xPos on Q and K (in place)
        xpos_kernel<<<(BSZ * SLEN * HEADS * 32) / 256, 256, 0, stream>>>(Qb, Kb);

        // attention -> AT (B,S,V_DIM)
        attn_kernel<<<dim3(SLEN, HEADS, BSZ), 256, 0, stream>>>(Qb, Kb, Vb, AT);

        // output projection -> P
        gemm64<0, 0><<<dim3(HIDDEN / 64, MROWS / 64), 256, 0, stream>>>(
            AT, Wo_l, nullptr, P, MROWS, HIDDEN, V_DIM);

        // Y = LN(A + P)
        addln_kernel<<<MROWS, 256, 0, stream>>>(A, P, g1_l, be1_l, Y);

        // F1 = relu(Y @ W1 + b1)
        gemm64<1, 1><<<dim3(FFN_DIM / 64, MROWS / 64), 256, 0, stream>>>(
            Y, W1_l, b1_l, F1, MROWS, FFN_DIM, HIDDEN);

        // F2 = F1 @ W2 + b2
        gemm64<1, 0><<<dim3(HIDDEN / 64, MROWS / 64), 256, 0, stream>>>(
            F1, W2_l, b2_l, F2, MROWS, HIDDEN, FFN_DIM);

        // x_next = LN(Y + F2)  -> A, or d_out for the last layer
        float* dst = (l == LAYERS - 1) ? out : A;
        addln_kernel<<<MROWS, 256, 0, stream>>>(Y, F2, g2_l, be2_l, dst);
    }
}

// Round 2
// 2752.301 us; speedup vs baseline: 4.9792x; 4.9792x over previous
//
#include <hip/hip_runtime.h>
#include <math.h>

#define LAYERS 2
#define HIDDEN 512
#define FFN_DIM 2048
#define HEADS 8
#define SLEN 2048
#define BSZ 2
#define KEY_DIM 64
#define V_DIM 1024
#define HEAD_SIZE 128
#define MROWS (BSZ * SLEN)          // 4096 rows
#define SCALE_BASE 512.0f
#define ATT_SCALING 0.125f          // KEY_DIM^-0.5
#define LN_EPS 1e-5f

// ---------------------------------------------------------------------------
// Tiled fp32 GEMM: C[M,N] = A[M,K] @ W[K,N] (+bias) (+relu)
// 64x64 output tile per 256-thread block, 4x4 register blocking.
// ---------------------------------------------------------------------------
template <int BIAS, int RELU>
__global__ __launch_bounds__(256) void gemm64(const float* __restrict__ A,
                                              const float* __restrict__ W,
                                              const float* __restrict__ bias,
                                              float* __restrict__ C,
                                              int M, int N, int K) {
    __shared__ float As[16][65];   // [k][m]
    __shared__ float Bs[16][64];   // [k][n]

    const int tid = threadIdx.x;
    const int tx = tid & 15;       // N direction
    const int ty = tid >> 4;       // M direction
    const int row0 = blockIdx.y * 64 + ty * 4;
    const int col0 = blockIdx.x * 64 + tx * 4;

    float acc[4][4] = {};

    for (int kt = 0; kt < K; kt += 16) {
#pragma unroll
        for (int i = 0; i < 4; i++) {
            int e = tid + i * 256;
            int m = e >> 4;
            int k = e & 15;
            As[k][m] = A[(size_t)(blockIdx.y * 64 + m) * K + kt + k];
        }
#pragma unroll
        for (int i = 0; i < 4; i++) {
            int e = tid + i * 256;
            int k = e >> 6;
            int n = e & 63;
            Bs[k][n] = W[(size_t)(kt + k) * N + blockIdx.x * 64 + n];
        }
        __syncthreads();
#pragma unroll
        for (int kk = 0; kk < 16; kk++) {
            float a[4], b[4];
#pragma unroll
            for (int i = 0; i < 4; i++) a[i] = As[kk][ty * 4 + i];
#pragma unroll
            for (int j = 0; j < 4; j++) b[j] = Bs[kk][tx * 4 + j];
#pragma unroll
            for (int i = 0; i < 4; i++)
#pragma unroll
                for (int j = 0; j < 4; j++) acc[i][j] += a[i] * b[j];
        }
        __syncthreads();
    }

#pragma unroll
    for (int i = 0; i < 4; i++) {
#pragma unroll
        for (int j = 0; j < 4; j++) {
            float v = acc[i][j];
            if (BIAS) v += bias[col0 + j];
            if (RELU) v = fmaxf(v, 0.0f);
            C[(size_t)(row0 + i) * N + col0 + j] = v;
        }
    }
}

// ---------------------------------------------------------------------------
// xPos rotary embedding applied in-place to Q and K.
// ---------------------------------------------------------------------------
__global__ __launch_bounds__(256) void xpos_kernel(float* __restrict__ Q,
                                                   float* __restrict__ K) {
    int idx = blockIdx.x * 256 + threadIdx.x;
    int j = idx & 31;
    int h = (idx >> 5) & 7;
    int s = (idx >> 8) & (SLEN - 1);
    int b = idx >> 19;

    float base = (2.0f * j + 0.4f * KEY_DIM) / (1.4f * KEY_DIM);
    float pos = (float)(s - SLEN / 2);
    float scale = powf(base, pos / SCALE_BASE);
    float inv_freq = powf(10000.0f, -(float)j / 32.0f);
    float ang = (float)s * inv_freq;
    float sn = sinf(ang) * scale;
    float cs = cosf(ang) * scale;

    size_t off = ((size_t)(b * SLEN + s)) * HIDDEN + h * KEY_DIM + 2 * j;

    float q0 = Q[off], q1 = Q[off + 1];
    Q[off]     = q0 * cs - q1 * sn;
    Q[off + 1] = q1 * cs + q0 * sn;

    float k0 = K[off], k1 = K[off + 1];
    K[off]     = k0 * cs - k1 * sn;
    K[off + 1] = k1 * cs + k0 * sn;
}

// ---------------------------------------------------------------------------
// Flash attention: one block per (b, h, 64-row q-tile). Iterate 64-key tiles,
// K/V staged in LDS (coalesced), online softmax, PV in registers.
// Thread map: tx = tid&15, ty = tid>>4.
//   S phase : thread computes s[4][4] for q = ty*4+i, k = tx*4+j
//   PV phase: thread owns  o[4][8]  for q = ty*4+i, v = tx + 16*j
// SCALING applied post-softmax (matches reference).
// ---------------------------------------------------------------------------
__global__ __launch_bounds__(256) void flash_attn(const float* __restrict__ Q,
                                                  const float* __restrict__ K,
                                                  const float* __restrict__ V,
                                                  float* __restrict__ O) {
    const int q0 = blockIdx.x * 64;
    const int h  = blockIdx.y;
    const int b  = blockIdx.z;
    const int tid = threadIdx.x;
    const int tx = tid & 15;
    const int ty = tid >> 4;

    __shared__ __align__(16) float Qs[64][68];   // pad 68 -> 16B-aligned rows
    __shared__ __align__(16) float KSs[64][68];  // K-tile, then S/P-tile
    __shared__ __align__(16) float Vs[64][128];
    __shared__ float alphaS[64];
    __shared__ float invS[64];

    // load Q tile (coalesced)
#pragma unroll
    for (int i = 0; i < 16; i++) {
        int e = tid + i * 256;       // 0..4095
        int r = e >> 6, d = e & 63;
        Qs[r][d] = Q[((size_t)(b * SLEN + q0 + r)) * HIDDEN + h * KEY_DIM + d];
    }

    float o[4][8];
#pragma unroll
    for (int i = 0; i < 4; i++)
#pragma unroll
        for (int j = 0; j < 8; j++) o[i][j] = 0.0f;
    float m = -1e30f, l = 0.0f;      // owned by threads 0..63 (row = tid)

    for (int kt = 0; kt < SLEN; kt += 64) {
        __syncthreads();             // previous iter done with KSs / Vs
        // load K tile
#pragma unroll
        for (int i = 0; i < 16; i++) {
            int e = tid + i * 256;
            int r = e >> 6, d = e & 63;
            KSs[r][d] = K[((size_t)(b * SLEN + kt + r)) * HIDDEN + h * KEY_DIM + d];
        }
        // load V tile
#pragma unroll
        for (int i = 0; i < 32; i++) {
            int e = tid + i * 256;   // 0..8191
            int r = e >> 7, v = e & 127;
            Vs[r][v] = V[((size_t)(b * SLEN + kt + r)) * V_DIM + h * HEAD_SIZE + v];
        }
        __syncthreads();

        // S-tile: 64x64, 4x4 per thread, float4 LDS reads over d
        float s[4][4];
#pragma unroll
        for (int i = 0; i < 4; i++)
#pragma unroll
            for (int j = 0; j < 4; j++) s[i][j] = 0.0f;
        for (int d = 0; d < 64; d += 4) {
            float4 a[4], bb[4];
#pragma unroll
            for (int i = 0; i < 4; i++) a[i] = *(const float4*)&Qs[ty * 4 + i][d];
#pragma unroll
            for (int j = 0; j < 4; j++) bb[j] = *(const float4*)&KSs[tx * 4 + j][d];
#pragma unroll
            for (int i = 0; i < 4; i++)
#pragma unroll
                for (int j = 0; j < 4; j++)
                    s[i][j] += a[i].x * bb[j].x + a[i].y * bb[j].y +
                               a[i].z * bb[j].z + a[i].w * bb[j].w;
        }
        __syncthreads();             // everyone done reading K-tile

        // spill S into the K-tile buffer
#pragma unroll
        for (int i = 0; i < 4; i++)
#pragma unroll
            for (int j = 0; j < 4; j++)
                KSs[ty * 4 + i][tx * 4 + j] = s[i][j];
        __syncthreads();

        // online softmax, one thread per q-row
        if (tid < 64) {
            float tmax = -1e30f;
#pragma unroll 8
            for (int k = 0; k < 64; k++) tmax = fmaxf(tmax, KSs[tid][k]);
            float mnew = fmaxf(m, tmax);
            float alpha = expf(m - mnew);
            float ls = 0.0f;
#pragma unroll 8
            for (int k = 0; k < 64; k++) {
                float e = expf(KSs[tid][k] - mnew);
                KSs[tid][k] = e;
                ls += e;
            }
            l = l * alpha + ls;
            m = mnew;
            alphaS[tid] = alpha;
        }
        __syncthreads();

        // rescale + accumulate PV
        float al[4];
#pragma unroll
        for (int i = 0; i < 4; i++) al[i] = alphaS[ty * 4 + i];
#pragma unroll
        for (int i = 0; i < 4; i++)
#pragma unroll
            for (int j = 0; j < 8; j++) o[i][j] *= al[i];

        for (int kk = 0; kk < 64; kk++) {
            float p[4], vv[8];
#pragma unroll
            for (int i = 0; i < 4; i++) p[i] = KSs[ty * 4 + i][kk];
#pragma unroll
            for (int j = 0; j < 8; j++) vv[j] = Vs[kk][tx + 16 * j];
#pragma unroll
            for (int i = 0; i < 4; i++)
#pragma unroll
                for (int j = 0; j < 8; j++) o[i][j] += p[i] * vv[j];
        }
    }

    if (tid < 64) invS[tid] = ATT_SCALING / l;
    __syncthreads();

#pragma unroll
    for (int i = 0; i < 4; i++) {
        float sc = invS[ty * 4 + i];
        size_t base = ((size_t)(b * SLEN + q0 + ty * 4 + i)) * V_DIM + h * HEAD_SIZE;
#pragma unroll
        for (int j = 0; j < 8; j++) O[base + tx + 16 * j] = o[i][j] * sc;
    }
}

// ---------------------------------------------------------------------------
// y = LayerNorm(X + R) * g + be    (one block per row of 512)
// ---------------------------------------------------------------------------
__global__ __launch_bounds__(256) void addln_kernel(const float* __restrict__ X,
                                                    const float* __restrict__ R,
                                                    const float* __restrict__ g,
                                                    const float* __restrict__ be,
                                                    float* __restrict__ O) {
    const int row = blockIdx.x;
    const int tid = threadIdx.x;
    __shared__ float red[256];

    size_t off = (size_t)row * HIDDEN;
    float v0 = X[off + tid] + R[off + tid];
    float v1 = X[off + tid + 256] + R[off + tid + 256];

    red[tid] = v0 + v1;
    __syncthreads();
    for (int s = 128; s > 0; s >>= 1) {
        if (tid < s) red[tid] += red[tid + s];
        __syncthreads();
    }
    float mu = red[0] * (1.0f / HIDDEN);
    __syncthreads();

    float d0 = v0 - mu, d1 = v1 - mu;
    red[tid] = d0 * d0 + d1 * d1;
    __syncthreads();
    for (int s = 128; s > 0; s >>= 1) {
        if (tid < s) red[tid] += red[tid + s];
        __syncthreads();
    }
    float rstd = rsqrtf(red[0] * (1.0f / HIDDEN) + LN_EPS);

    O[off + tid]       = d0 * rstd * g[tid] + be[tid];
    O[off + tid + 256] = d1 * rstd * g[tid + 256] + be[tid + 256];
}

// ---------------------------------------------------------------------------
extern "C" void kernel_launch(void* const* d_in, const int* in_sizes, int n_in,
                              void* d_out, int out_size, void* d_ws, size_t ws_size,
                              hipStream_t stream) {
    const float* x   = (const float*)d_in[0];
    const float* Wq  = (const float*)d_in[1];
    const float* Wk  = (const float*)d_in[2];
    const float* Wv  = (const float*)d_in[3];
    const float* Wo  = (const float*)d_in[4];
    const float* W1  = (const float*)d_in[5];
    const float* b1  = (const float*)d_in[6];
    const float* W2  = (const float*)d_in[7];
    const float* b2  = (const float*)d_in[8];
    const float* g1  = (const float*)d_in[9];
    const float* be1 = (const float*)d_in[10];
    const float* g2  = (const float*)d_in[11];
    const float* be2 = (const float*)d_in[12];
    float* out = (float*)d_out;

    const size_t M1 = 1024 * 1024;
    float* ws = (float*)d_ws;
    float* A  = ws;                  // 2M floats : current x
    float* Y  = ws + 2 * M1;         // 2M : post-attn LN output
    float* Qb = ws + 4 * M1;         // 2M
    float* Kb = ws + 6 * M1;         // 2M
    float* Vb = ws + 8 * M1;         // 4M
    float* AT = ws + 12 * M1;        // 4M : attention out (B,S,V_DIM)
    float* P  = Kb;                  // attn projection (K dead by then)
    float* F1 = Qb;                  // FFN hidden (Q/K/V dead by then)
    float* F2 = AT;                  // FFN out (AT dead by then)

    hipMemcpyAsync(A, x, (size_t)MROWS * HIDDEN * sizeof(float),
                   hipMemcpyDeviceToDevice, stream);

    for (int l = 0; l < LAYERS; l++) {
        const float* Wq_l  = Wq + (size_t)l * HIDDEN * HIDDEN;
        const float* Wk_l  = Wk + (size_t)l * HIDDEN * HIDDEN;
        const float* Wv_l  = Wv + (size_t)l * HIDDEN * V_DIM;
        const float* Wo_l  = Wo + (size_t)l * V_DIM * HIDDEN;
        const float* W1_l  = W1 + (size_t)l * HIDDEN * FFN_DIM;
        const float* b1_l  = b1 + (size_t)l * FFN_DIM;
        const float* W2_l  = W2 + (size_t)l * FFN_DIM * HIDDEN;
        const float* b2_l  = b2 + (size_t)l * HIDDEN;
        const float* g1_l  = g1 + (size_t)l * HIDDEN;
        const float* be1_l = be1 + (size_t)l * HIDDEN;
        const float* g2_l  = g2 + (size_t)l * HIDDEN;
        const float* be2_l = be2 + (size_t)l * HIDDEN;

        gemm64<0, 0><<<dim3(HIDDEN / 64, MROWS / 64), 256, 0, stream>>>(
            A, Wq_l, nullptr, Qb, MROWS, HIDDEN, HIDDEN);
        gemm64<0, 0><<<dim3(HIDDEN / 64, MROWS / 64), 256, 0, stream>>>(
            A, Wk_l, nullptr, Kb, MROWS, HIDDEN, HIDDEN);
        gemm64<0, 0><<<dim3(V_DIM / 64, MROWS / 64), 256, 0, stream>>>(
            A, Wv_l, nullptr, Vb, MROWS, V_DIM, HIDDEN);

        xpos_kernel<<<(BSZ * SLEN * HEADS * 32) / 256, 256, 0, stream>>>(Qb, Kb);

        flash_attn<<<dim3(SLEN / 64, HEADS, BSZ), 256, 0, stream>>>(Qb, Kb, Vb, AT);

        gemm64<0, 0><<<dim3(HIDDEN / 64, MROWS / 64), 256, 0, stream>>>(
            AT, Wo_l, nullptr, P, MROWS, HIDDEN, V_DIM);

        addln_kernel<<<MROWS, 256, 0, stream>>>(A, P, g1_l, be1_l, Y);

        gemm64<1, 1><<<dim3(FFN_DIM / 64, MROWS / 64), 256, 0, stream>>>(
            Y, W1_l, b1_l, F1, MROWS, FFN_DIM, HIDDEN);

        gemm64<1, 0><<<dim3(HIDDEN / 64, MROWS / 64), 256, 0, stream>>>(
            F1, W2_l, b2_l, F2, MROWS, HIDDEN, FFN_DIM);

        float* dst = (l == LAYERS - 1) ? out : A;
        addln_kernel<<<MROWS, 256, 0, stream>>>(Y, F2, g2_l, be2_l, dst);
    }
}

// Round 3
// 580.925 us; speedup vs baseline: 23.5903x; 4.7378x over previous
//
#include <hip/hip_runtime.h>
#include <math.h>

#define LAYERS 2
#define HIDDEN 512
#define FFN_DIM 2048
#define HEADS 8
#define SLEN 2048
#define BSZ 2
#define MROWS 4096
#define ATT_SCALING 0.125f
#define LN_EPS 1e-5f
#define SCALE_BASE 512.0f

typedef unsigned short u16;
typedef __attribute__((ext_vector_type(8))) short bf16x8;   // 8 bf16 = 4 VGPR
typedef __attribute__((ext_vector_type(4))) float f32x4;

__device__ __forceinline__ float bf2f(u16 u) {
    union { unsigned int i; float f; } v; v.i = ((unsigned int)u) << 16; return v.f;
}
__device__ __forceinline__ u16 f2bf(float f) {
    union { float f; unsigned int i; } v; v.f = f;
    unsigned int r = v.i + 0x7FFFu + ((v.i >> 16) & 1u);   // RNE
    return (u16)(r >> 16);
}
__device__ __forceinline__ void async16(const void* g, void* l) {
    __builtin_amdgcn_global_load_lds((const __attribute__((address_space(1))) void*)g,
                                     (__attribute__((address_space(3))) void*)l, 16, 0, 0);
}

// ---------------------------------------------------------------------------
// fp32 [K][N] -> bf16 [N][K] transpose (weights prep)
// ---------------------------------------------------------------------------
__global__ __launch_bounds__(256) void wtrans(const float* __restrict__ in,
                                              u16* __restrict__ out,
                                              int K, int N) {
    __shared__ float t[32][33];
    int tx = threadIdx.x & 31, ty = threadIdx.x >> 5;       // 32 x 8
    int k0 = blockIdx.y * 32, n0 = blockIdx.x * 32;
#pragma unroll
    for (int i = 0; i < 4; i++)
        t[ty + 8 * i][tx] = in[(size_t)(k0 + ty + 8 * i) * N + n0 + tx];
    __syncthreads();
#pragma unroll
    for (int i = 0; i < 4; i++)
        out[(size_t)(n0 + ty + 8 * i) * K + k0 + tx] = f2bf(t[tx][ty + 8 * i]);
}

// ---------------------------------------------------------------------------
// x fp32 -> residual fp32 copy + bf16 copy
// ---------------------------------------------------------------------------
__global__ __launch_bounds__(256) void cvt_x(const float* __restrict__ x,
                                             float* __restrict__ Af,
                                             u16* __restrict__ Ab) {
    int i = blockIdx.x * 256 + threadIdx.x;
    float v = x[i];
    Af[i] = v;
    Ab[i] = f2bf(v);
}

// ---------------------------------------------------------------------------
// MFMA GEMM: C[M,N] = A[M,K] @ W[K,N], W given as WT[N][K] (both bf16).
// BK=32, global_load_lds staging (m97 structure). BM=128: 2x2 waves of 64x64.
// BM=64: 4 waves side-by-side, each 64x32.
// ---------------------------------------------------------------------------
template <int BM, int BN, int OUTF32, int BIAS, int RELU>
__global__ __launch_bounds__(256) void gemm_mfma(const u16* __restrict__ A,
                                                 const u16* __restrict__ WT,
                                                 const float* __restrict__ bias,
                                                 void* __restrict__ Cout,
                                                 int M, int N, int K) {
    constexpr int AM = 4;
    constexpr int AN = (BM == 128) ? 4 : 2;
    constexpr int AIT = BM / 64;
    constexpr int BIT = BN / 64;

    __shared__ u16 As[BM * 32];
    __shared__ u16 Bs[BN * 32];

    const int tid  = threadIdx.x;
    const int wave = tid >> 6;
    const int lane = tid & 63;
    const int quad = lane >> 4;
    const int l15  = lane & 15;
    const int wm = (BM == 128) ? (wave & 1) : 0;
    const int wn = (BM == 128) ? (wave >> 1) : wave;

    const int tm = blockIdx.y * BM;
    const int tn = blockIdx.x * BN;

    f32x4 acc[AM][AN];
#pragma unroll
    for (int i = 0; i < AM; i++)
#pragma unroll
        for (int j = 0; j < AN; j++) acc[i][j] = (f32x4){0.f, 0.f, 0.f, 0.f};

    for (int kt = 0; kt < K; kt += 32) {
        __syncthreads();
#pragma unroll
        for (int it = 0; it < AIT; it++) {
            int cid = it * 256 + tid;
            int m = cid >> 2, q = cid & 3;
            async16(A + (size_t)(tm + m) * K + kt + q * 8,
                    (char*)As + (it * 256 + wave * 64) * 16);
        }
#pragma unroll
        for (int it = 0; it < BIT; it++) {
            int cid = it * 256 + tid;
            int n = cid >> 2, q = cid & 3;
            async16(WT + (size_t)(tn + n) * K + kt + q * 8,
                    (char*)Bs + (it * 256 + wave * 64) * 16);
        }
        __syncthreads();

        bf16x8 af[AM], bfr[AN];
#pragma unroll
        for (int i = 0; i < AM; i++)
            af[i] = *(const bf16x8*)((const char*)As +
                     ((wm * 64 + i * 16 + l15) * 4 + quad) * 16);
#pragma unroll
        for (int j = 0; j < AN; j++)
            bfr[j] = *(const bf16x8*)((const char*)Bs +
                     ((wn * (AN * 16) + j * 16 + l15) * 4 + quad) * 16);
#pragma unroll
        for (int i = 0; i < AM; i++)
#pragma unroll
            for (int j = 0; j < AN; j++)
                acc[i][j] = __builtin_amdgcn_mfma_f32_16x16x32_bf16(af[i], bfr[j],
                                                                    acc[i][j], 0, 0, 0);
    }

#pragma unroll
    for (int i = 0; i < AM; i++) {
#pragma unroll
        for (int j = 0; j < AN; j++) {
            int col = tn + wn * (AN * 16) + j * 16 + l15;
            float bv = BIAS ? bias[col] : 0.0f;
#pragma unroll
            for (int r = 0; r < 4; r++) {
                int row = tm + wm * 64 + i * 16 + quad * 4 + r;
                float v = acc[i][j][r] + bv;
                if (RELU) v = fmaxf(v, 0.0f);
                if (OUTF32) ((float*)Cout)[(size_t)row * N + col] = v;
                else        ((u16*)Cout)[(size_t)row * N + col] = f2bf(v);
            }
        }
    }
}

// ---------------------------------------------------------------------------
// xPos applied in-place to Q (cols h*64+..) and K (cols 512+h*64+..) of QKV bf16
// ---------------------------------------------------------------------------
__global__ __launch_bounds__(256) void xpos_kernel(u16* __restrict__ QKV) {
    int idx = blockIdx.x * 256 + threadIdx.x;   // 2^20
    int j = idx & 31;
    int h = (idx >> 5) & 7;
    int s = (idx >> 8) & 2047;
    int b = idx >> 19;

    float base = (2.0f * j + 0.4f * 64.0f) / (1.4f * 64.0f);
    float pos = (float)(s - 1024);
    float scale = powf(base, pos / SCALE_BASE);
    float inv_freq = powf(10000.0f, -(float)j / 32.0f);
    float ang = (float)s * inv_freq;
    float sn = sinf(ang) * scale;
    float cs = cosf(ang) * scale;

    size_t off = (size_t)(b * SLEN + s) * 2048 + h * 64 + 2 * j;
    float q0 = bf2f(QKV[off]), q1 = bf2f(QKV[off + 1]);
    QKV[off]     = f2bf(q0 * cs - q1 * sn);
    QKV[off + 1] = f2bf(q1 * cs + q0 * sn);
    float k0 = bf2f(QKV[off + 512]), k1 = bf2f(QKV[off + 513]);
    QKV[off + 512] = f2bf(k0 * cs - k1 * sn);
    QKV[off + 513] = f2bf(k1 * cs + k0 * sn);
}

// ---------------------------------------------------------------------------
// V section of QKV -> VT[(b*8+h)*128 + v][s]  (bf16 -> bf16 transpose)
// ---------------------------------------------------------------------------
__global__ __launch_bounds__(256) void vtrans(const u16* __restrict__ QKV,
                                              u16* __restrict__ VT) {
    __shared__ u16 t[64][65];
    int b = blockIdx.z >> 3, h = blockIdx.z & 7;
    int s0 = blockIdx.x * 64, v0 = blockIdx.y * 64;
    int tid = threadIdx.x;
#pragma unroll
    for (int i = 0; i < 16; i++) {
        int e = tid + i * 256; int r = e >> 6, c = e & 63;      // r: s, c: v
        t[r][c] = QKV[(size_t)(b * SLEN + s0 + r) * 2048 + 1024 + h * 128 + v0 + c];
    }
    __syncthreads();
#pragma unroll
    for (int i = 0; i < 16; i++) {
        int e = tid + i * 256; int r = e >> 6, c = e & 63;      // r: v, c: s
        VT[(size_t)((b * 8 + h) * 128 + v0 + r) * 2048 + s0 + c] = t[c][r];
    }
}

// ---------------------------------------------------------------------------
// MFMA flash attention. Block = (b, h, 64-q tile); wave owns 16 q-rows.
// K-tile + VT-tile staged via global_load_lds; softmax in registers
// (shfl over 16-lane quad groups); P via per-wave padded LDS round trip.
// ---------------------------------------------------------------------------
__global__ __launch_bounds__(256) void flash_attn_mfma(const u16* __restrict__ QKV,
                                                       const u16* __restrict__ VT,
                                                       u16* __restrict__ O) {
    const int q0 = blockIdx.x * 64;
    const int h  = blockIdx.y;
    const int b  = blockIdx.z;
    const int tid  = threadIdx.x;
    const int wave = tid >> 6;
    const int lane = tid & 63;
    const int quad = lane >> 4;
    const int l15  = lane & 15;

    __shared__ u16 Ks[64 * 64];      // 2 d-subtiles x 256 chunks (8 KB)
    __shared__ u16 Vs[128 * 64];     // 2 k-subtiles x 512 chunks (16 KB)
    __shared__ u16 Pl[4][16 * 72];   // per-wave P, padded rows (9 KB)

    bf16x8 qf[2];
    {
        const u16* p = QKV + (size_t)(b * SLEN + q0 + wave * 16 + l15) * 2048 +
                       h * 64 + quad * 8;
        qf[0] = *(const bf16x8*)p;
        qf[1] = *(const bf16x8*)(p + 32);
    }

    f32x4 o_acc[8];
#pragma unroll
    for (int t = 0; t < 8; t++) o_acc[t] = (f32x4){0.f, 0.f, 0.f, 0.f};
    float m_r[4] = {-1e30f, -1e30f, -1e30f, -1e30f};
    float l_r[4] = {0.f, 0.f, 0.f, 0.f};

    for (int kt = 0; kt < SLEN; kt += 64) {
        __syncthreads();
#pragma unroll
        for (int it = 0; it < 2; it++) {
            int cid = it * 256 + tid;
            int c = cid >> 8, p = cid & 255;
            int kr = p >> 2, q = p & 3;
            async16(QKV + (size_t)(b * SLEN + kt + kr) * 2048 + 512 + h * 64 +
                        c * 32 + q * 8,
                    (char*)Ks + (it * 256 + wave * 64) * 16);
        }
#pragma unroll
        for (int it = 0; it < 4; it++) {
            int cid = it * 256 + tid;
            int c = cid >> 9, p = cid & 511;
            int vr = p >> 2, q = p & 3;
            async16(VT + (size_t)((b * 8 + h) * 128 + vr) * 2048 + kt + c * 32 + q * 8,
                    (char*)Vs + (it * 256 + wave * 64) * 16);
        }
        __syncthreads();

        // S = Q K^T  (rows quad*4+r, cols t*16+l15)
        f32x4 s_acc[4];
#pragma unroll
        for (int t = 0; t < 4; t++) s_acc[t] = (f32x4){0.f, 0.f, 0.f, 0.f};
#pragma unroll
        for (int c = 0; c < 2; c++)
#pragma unroll
            for (int t = 0; t < 4; t++) {
                bf16x8 kb = *(const bf16x8*)((const char*)Ks + c * 4096 +
                             ((t * 16 + l15) * 4 + quad) * 16);
                s_acc[t] = __builtin_amdgcn_mfma_f32_16x16x32_bf16(qf[c], kb,
                                                                   s_acc[t], 0, 0, 0);
            }

        // online softmax per q-row (replicated across the 16 lanes of each quad)
        float alpha[4];
#pragma unroll
        for (int r = 0; r < 4; r++) {
            float mx = fmaxf(fmaxf(s_acc[0][r], s_acc[1][r]),
                             fmaxf(s_acc[2][r], s_acc[3][r]));
#pragma unroll
            for (int off = 1; off < 16; off <<= 1) mx = fmaxf(mx, __shfl_xor(mx, off, 64));
            float mnew = fmaxf(m_r[r], mx);
            alpha[r] = expf(m_r[r] - mnew);
            float ls = 0.f;
#pragma unroll
            for (int t = 0; t < 4; t++) {
                float pv = expf(s_acc[t][r] - mnew);
                ls += pv;
                Pl[wave][(quad * 4 + r) * 72 + t * 16 + l15] = f2bf(pv);
            }
#pragma unroll
            for (int off = 1; off < 16; off <<= 1) ls += __shfl_xor(ls, off, 64);
            l_r[r] = l_r[r] * alpha[r] + ls;
            m_r[r] = mnew;
        }
#pragma unroll
        for (int t = 0; t < 8; t++)
#pragma unroll
            for (int r = 0; r < 4; r++) o_acc[t][r] *= alpha[r];

        __asm__ volatile("s_waitcnt lgkmcnt(0)" ::: "memory");  // P writes -> reads (wave-local)

        // O += P V
#pragma unroll
        for (int c = 0; c < 2; c++) {
            bf16x8 pf = *(const bf16x8*)((const char*)&Pl[wave][0] +
                         l15 * 144 + c * 64 + quad * 16);
#pragma unroll
            for (int t = 0; t < 8; t++) {
                bf16x8 vb = *(const bf16x8*)((const char*)Vs + c * 8192 +
                             ((t * 16 + l15) * 4 + quad) * 16);
                o_acc[t] = __builtin_amdgcn_mfma_f32_16x16x32_bf16(pf, vb,
                                                                   o_acc[t], 0, 0, 0);
            }
        }
    }

#pragma unroll
    for (int r = 0; r < 4; r++) {
        float inv = ATT_SCALING / l_r[r];
        size_t base = (size_t)(b * SLEN + q0 + wave * 16 + quad * 4 + r) * 1024 + h * 128;
#pragma unroll
        for (int t = 0; t < 8; t++)
            O[base + t * 16 + l15] = f2bf(o_acc[t][r] * inv);
    }
}

// ---------------------------------------------------------------------------
// LN(X + R) * g + be : fp32 in, fp32 + bf16 out (one block per 512-row)
// ---------------------------------------------------------------------------
__global__ __launch_bounds__(256) void addln_kernel(const float* __restrict__ X,
                                                    const float* __restrict__ R,
                                                    const float* __restrict__ g,
                                                    const float* __restrict__ be,
                                                    float* __restrict__ dstf,
                                                    u16* __restrict__ dstb) {
    const int row = blockIdx.x;
    const int tid = threadIdx.x;
    __shared__ float red[256];
    size_t off = (size_t)row * HIDDEN;
    float v0 = X[off + tid] + R[off + tid];
    float v1 = X[off + tid + 256] + R[off + tid + 256];
    red[tid] = v0 + v1;
    __syncthreads();
    for (int s = 128; s > 0; s >>= 1) { if (tid < s) red[tid] += red[tid + s]; __syncthreads(); }
    float mu = red[0] * (1.0f / HIDDEN);
    __syncthreads();
    float d0 = v0 - mu, d1 = v1 - mu;
    red[tid] = d0 * d0 + d1 * d1;
    __syncthreads();
    for (int s = 128; s > 0; s >>= 1) { if (tid < s) red[tid] += red[tid + s]; __syncthreads(); }
    float rstd = rsqrtf(red[0] * (1.0f / HIDDEN) + LN_EPS);
    float o0 = d0 * rstd * g[tid] + be[tid];
    float o1 = d1 * rstd * g[tid + 256] + be[tid + 256];
    dstf[off + tid] = o0;
    dstf[off + tid + 256] = o1;
    dstb[off + tid] = f2bf(o0);
    dstb[off + tid + 256] = f2bf(o1);
}

// ---------------------------------------------------------------------------
extern "C" void kernel_launch(void* const* d_in, const int* in_sizes, int n_in,
                              void* d_out, int out_size, void* d_ws, size_t ws_size,
                              hipStream_t stream) {
    const float* x   = (const float*)d_in[0];
    const float* Wq  = (const float*)d_in[1];
    const float* Wk  = (const float*)d_in[2];
    const float* Wv  = (const float*)d_in[3];
    const float* Wo  = (const float*)d_in[4];
    const float* W1  = (const float*)d_in[5];
    const float* b1  = (const float*)d_in[6];
    const float* W2  = (const float*)d_in[7];
    const float* b2  = (const float*)d_in[8];
    const float* g1  = (const float*)d_in[9];
    const float* be1 = (const float*)d_in[10];
    const float* g2  = (const float*)d_in[11];
    const float* be2 = (const float*)d_in[12];
    float* out = (float*)d_out;

    // Workspace layout (62 MB, lifetime-disjoint aliases):
    //  R1 [ 0..8M)  : A_f32 residual  -> F2 fp32 -> A_f32(next, elementwise-safe)
    //  R2 [ 8..16M) : VT (attn)       -> Y_f32
    //  R3 [16..24M) : A_bf (4M)       -> P fp32 (8M)
    //  R4 [24..40M) : QKV bf16 (16M)  -> F1 bf16
    //  R5 [40..48M) : AT bf16 (8M)    -> Y_bf (4M)
    //  R6 [48..62M) : bf16 transposed weights
    const size_t MB = 1u << 20;
    char* w = (char*)d_ws;
    float* R1f  = (float*)(w);
    u16*   VTg  = (u16*)(w + 8 * MB);
    float* Yf   = (float*)(w + 8 * MB);
    u16*   A_bf = (u16*)(w + 16 * MB);
    float* Pf   = (float*)(w + 16 * MB);
    u16*   QKV  = (u16*)(w + 24 * MB);
    u16*   F1   = (u16*)(w + 24 * MB);
    u16*   AT   = (u16*)(w + 40 * MB);
    u16*   Y_bf = (u16*)(w + 40 * MB);

    cvt_x<<<MROWS * HIDDEN / 256, 256, 0, stream>>>(x, R1f, A_bf);

    // weight prep: transpose + bf16
    for (int l = 0; l < LAYERS; l++) {
        u16* WqkvT = (u16*)(w + 48 * MB + (size_t)l * 2 * MB);
        u16* WoT   = (u16*)(w + 52 * MB + (size_t)l * 1 * MB);
        u16* W1T   = (u16*)(w + 54 * MB + (size_t)l * 2 * MB);
        u16* W2T   = (u16*)(w + 58 * MB + (size_t)l * 2 * MB);
        wtrans<<<dim3(16, 16), 256, 0, stream>>>(Wq + (size_t)l * 512 * 512,  WqkvT,              512, 512);
        wtrans<<<dim3(16, 16), 256, 0, stream>>>(Wk + (size_t)l * 512 * 512,  WqkvT + 512 * 512,  512, 512);
        wtrans<<<dim3(32, 16), 256, 0, stream>>>(Wv + (size_t)l * 512 * 1024, WqkvT + 1024 * 512, 512, 1024);
        wtrans<<<dim3(16, 32), 256, 0, stream>>>(Wo + (size_t)l * 1024 * 512, WoT,                1024, 512);
        wtrans<<<dim3(64, 16), 256, 0, stream>>>(W1 + (size_t)l * 512 * 2048, W1T,                512, 2048);
        wtrans<<<dim3(16, 64), 256, 0, stream>>>(W2 + (size_t)l * 2048 * 512, W2T,                2048, 512);
    }

    for (int l = 0; l < LAYERS; l++) {
        u16* WqkvT = (u16*)(w + 48 * MB + (size_t)l * 2 * MB);
        u16* WoT   = (u16*)(w + 52 * MB + (size_t)l * 1 * MB);
        u16* W1T   = (u16*)(w + 54 * MB + (size_t)l * 2 * MB);
        u16* W2T   = (u16*)(w + 58 * MB + (size_t)l * 2 * MB);
        const float* b1_l  = b1 + (size_t)l * FFN_DIM;
        const float* b2_l  = b2 + (size_t)l * HIDDEN;
        const float* g1_l  = g1 + (size_t)l * HIDDEN;
        const float* be1_l = be1 + (size_t)l * HIDDEN;
        const float* g2_l  = g2 + (size_t)l * HIDDEN;
        const float* be2_l = be2 + (size_t)l * HIDDEN;

        // QKV = A_bf @ [Wq|Wk|Wv]  (bf16 out)
        gemm_mfma<128, 128, 0, 0, 0><<<dim3(16, 32), 256, 0, stream>>>(
            A_bf, WqkvT, nullptr, QKV, MROWS, 2048, 512);

        xpos_kernel<<<4096, 256, 0, stream>>>(QKV);
        vtrans<<<dim3(32, 2, 16), 256, 0, stream>>>(QKV, VTg);

        flash_attn_mfma<<<dim3(32, 8, 2), 256, 0, stream>>>(QKV, VTg, AT);

        // P = AT @ Wo (fp32 out)
        gemm_mfma<64, 128, 1, 0, 0><<<dim3(4, 64), 256, 0, stream>>>(
            AT, WoT, nullptr, Pf, MROWS, 512, 1024);

        // Y = LN(A + P)
        addln_kernel<<<MROWS, 256, 0, stream>>>(R1f, Pf, g1_l, be1_l, Yf, Y_bf);

        // F1 = relu(Y @ W1 + b1) (bf16 out)
        gemm_mfma<128, 128, 0, 1, 1><<<dim3(16, 32), 256, 0, stream>>>(
            Y_bf, W1T, b1_l, F1, MROWS, 2048, 512);

        // F2 = F1 @ W2 + b2 (fp32 out)
        gemm_mfma<64, 128, 1, 1, 0><<<dim3(4, 64), 256, 0, stream>>>(
            F1, W2T, b2_l, R1f, MROWS, 512, 2048);

        // x_next = LN(Y + F2)
        float* dstf = (l == LAYERS - 1) ? out : R1f;
        addln_kernel<<<MROWS, 256, 0, stream>>>(Yf, R1f, g2_l, be2_l, dstf, A_bf);
    }
}

// Round 4
// 498.558 us; speedup vs baseline: 27.4878x; 1.1652x over previous
//
#include <hip/hip_runtime.h>
#include <math.h>

#define LAYERS 2
#define HIDDEN 512
#define FFN_DIM 2048
#define HEADS 8
#define SLEN 2048
#define BSZ 2
#define MROWS 4096
#define ATT_SCALING 0.125f
#define LN_EPS 1e-5f
#define SCALE_BASE 512.0f

typedef unsigned short u16;
typedef unsigned int u32;
typedef __attribute__((ext_vector_type(8))) short bf16x8;   // 8 bf16 = 4 VGPR
typedef __attribute__((ext_vector_type(4))) float f32x4;

__device__ __forceinline__ float bf2f(u16 u) {
    union { u32 i; float f; } v; v.i = ((u32)u) << 16; return v.f;
}
__device__ __forceinline__ u16 f2bf(float f) {
    union { float f; u32 i; } v; v.f = f;
    u32 r = v.i + 0x7FFFu + ((v.i >> 16) & 1u);   // RNE
    return (u16)(r >> 16);
}
__device__ __forceinline__ void async16(const void* g, void* l) {
    __builtin_amdgcn_global_load_lds((const __attribute__((address_space(1))) void*)g,
                                     (__attribute__((address_space(3))) void*)l, 16, 0, 0);
}

// ---------------------------------------------------------------------------
// fp32 [K][N] -> bf16 [N][K] transpose (weights prep)
// ---------------------------------------------------------------------------
__global__ __launch_bounds__(256) void wtrans(const float* __restrict__ in,
                                              u16* __restrict__ out,
                                              int K, int N) {
    __shared__ float t[32][33];
    int tx = threadIdx.x & 31, ty = threadIdx.x >> 5;       // 32 x 8
    int k0 = blockIdx.y * 32, n0 = blockIdx.x * 32;
#pragma unroll
    for (int i = 0; i < 4; i++)
        t[ty + 8 * i][tx] = in[(size_t)(k0 + ty + 8 * i) * N + n0 + tx];
    __syncthreads();
#pragma unroll
    for (int i = 0; i < 4; i++)
        out[(size_t)(n0 + ty + 8 * i) * K + k0 + tx] = f2bf(t[tx][ty + 8 * i]);
}

// ---------------------------------------------------------------------------
// x fp32 -> residual fp32 copy + bf16 copy
// ---------------------------------------------------------------------------
__global__ __launch_bounds__(256) void cvt_x(const float* __restrict__ x,
                                             float* __restrict__ Af,
                                             u16* __restrict__ Ab) {
    int i = blockIdx.x * 256 + threadIdx.x;
    float v = x[i];
    Af[i] = v;
    Ab[i] = f2bf(v);
}

// ---------------------------------------------------------------------------
// xPos cos/sin table: tab[s*32+j] = (cos*scale, sin*scale)
// ---------------------------------------------------------------------------
__global__ __launch_bounds__(256) void xpos_table(float2* __restrict__ tab) {
    int idx = blockIdx.x * 256 + threadIdx.x;   // 2048*32 = 65536
    int j = idx & 31;
    int s = idx >> 5;
    float base = (2.0f * j + 0.4f * 64.0f) / (1.4f * 64.0f);
    float pos = (float)(s - 1024);
    float scale = powf(base, pos / SCALE_BASE);
    float inv_freq = powf(10000.0f, -(float)j / 32.0f);
    float ang = (float)s * inv_freq;
    tab[idx] = make_float2(cosf(ang) * scale, sinf(ang) * scale);
}

// ---------------------------------------------------------------------------
// xPos applied in-place to Q (cols h*64+..) and K (cols 512+h*64+..) of QKV
// bf16, packed u32 accesses.
// ---------------------------------------------------------------------------
__global__ __launch_bounds__(256) void xpos_kernel(u16* __restrict__ QKV,
                                                   const float2* __restrict__ tab) {
    int idx = blockIdx.x * 256 + threadIdx.x;   // 2^20
    int j = idx & 31;
    int h = (idx >> 5) & 7;
    int s = (idx >> 8) & 2047;
    int b = idx >> 19;

    float2 cssn = tab[s * 32 + j];
    float cs = cssn.x, sn = cssn.y;

    size_t off = (size_t)(b * SLEN + s) * 2048 + h * 64 + 2 * j;
    u32* pq = (u32*)(QKV + off);
    u32* pk = (u32*)(QKV + off + 512);

    u32 qv = *pq;
    float q0 = bf2f((u16)(qv & 0xffff)), q1 = bf2f((u16)(qv >> 16));
    *pq = (u32)f2bf(q0 * cs - q1 * sn) | ((u32)f2bf(q1 * cs + q0 * sn) << 16);

    u32 kv = *pk;
    float k0 = bf2f((u16)(kv & 0xffff)), k1 = bf2f((u16)(kv >> 16));
    *pk = (u32)f2bf(k0 * cs - k1 * sn) | ((u32)f2bf(k1 * cs + k0 * sn) << 16);
}

// ---------------------------------------------------------------------------
// V section of QKV -> VT[(b*8+h)*128 + v][s]  (bf16 -> bf16 transpose)
// ---------------------------------------------------------------------------
__global__ __launch_bounds__(256) void vtrans(const u16* __restrict__ QKV,
                                              u16* __restrict__ VT) {
    __shared__ u16 t[64][65];
    int b = blockIdx.z >> 3, h = blockIdx.z & 7;
    int s0 = blockIdx.x * 64, v0 = blockIdx.y * 64;
    int tid = threadIdx.x;
#pragma unroll
    for (int i = 0; i < 16; i++) {
        int e = tid + i * 256; int r = e >> 6, c = e & 63;      // r: s, c: v
        t[r][c] = QKV[(size_t)(b * SLEN + s0 + r) * 2048 + 1024 + h * 128 + v0 + c];
    }
    __syncthreads();
#pragma unroll
    for (int i = 0; i < 16; i++) {
        int e = tid + i * 256; int r = e >> 6, c = e & 63;      // r: v, c: s
        VT[(size_t)((b * 8 + h) * 128 + v0 + r) * 2048 + s0 + c] = t[c][r];
    }
}

// ---------------------------------------------------------------------------
// MFMA GEMM, software-pipelined: single barrier per K-tile, loads for tile
// t+1 issued after the barrier so they stay in flight across compute(t).
// C[M,N] = A[M,K] @ W[K,N], W given as WT[N][K] (both bf16). BK=32.
// Wave grid WM x WN (WM*WN = 4); wave tile (BM/WM) x (BN/WN).
// ---------------------------------------------------------------------------
template <int BM, int BN, int WM, int OUTF32, int BIAS, int RELU>
__global__ __launch_bounds__(256) void gemm_mfma(const u16* __restrict__ A,
                                                 const u16* __restrict__ WT,
                                                 const float* __restrict__ bias,
                                                 void* __restrict__ Cout,
                                                 int M, int N, int K) {
    constexpr int WN = 4 / WM;
    constexpr int AM = BM / (WM * 16);
    constexpr int AN = BN / (WN * 16);
    constexpr int AIT = BM / 64;
    constexpr int BIT = BN / 64;

    __shared__ u16 As[2][BM * 32];
    __shared__ u16 Bs[2][BN * 32];

    const int tid  = threadIdx.x;
    const int wave = tid >> 6;
    const int lane = tid & 63;
    const int quad = lane >> 4;
    const int l15  = lane & 15;
    const int wm = wave % WM;
    const int wn = wave / WM;

    const int tm = blockIdx.y * BM;
    const int tn = blockIdx.x * BN;

    auto issue = [&](int kt, int buf) {
#pragma unroll
        for (int it = 0; it < AIT; it++) {
            int cid = it * 256 + tid;
            async16(A + (size_t)(tm + (cid >> 2)) * K + kt + (cid & 3) * 8,
                    (char*)As[buf] + (it * 256 + wave * 64) * 16);
        }
#pragma unroll
        for (int it = 0; it < BIT; it++) {
            int cid = it * 256 + tid;
            async16(WT + (size_t)(tn + (cid >> 2)) * K + kt + (cid & 3) * 8,
                    (char*)Bs[buf] + (it * 256 + wave * 64) * 16);
        }
    };

    f32x4 acc[AM][AN];
#pragma unroll
    for (int i = 0; i < AM; i++)
#pragma unroll
        for (int j = 0; j < AN; j++) acc[i][j] = (f32x4){0.f, 0.f, 0.f, 0.f};

    const int nk = K >> 5;
    issue(0, 0);

    for (int t = 0; t < nk; t++) {
        __syncthreads();             // implicit vmcnt(0) drain: loads(t) done
        if (t + 1 < nk) issue((t + 1) << 5, (t + 1) & 1);
        const int buf = t & 1;

        bf16x8 af[AM], bfr[AN];
#pragma unroll
        for (int i = 0; i < AM; i++)
            af[i] = *(const bf16x8*)((const char*)As[buf] +
                     ((wm * (AM * 16) + i * 16 + l15) * 4 + quad) * 16);
#pragma unroll
        for (int j = 0; j < AN; j++)
            bfr[j] = *(const bf16x8*)((const char*)Bs[buf] +
                     ((wn * (AN * 16) + j * 16 + l15) * 4 + quad) * 16);
#pragma unroll
        for (int i = 0; i < AM; i++)
#pragma unroll
            for (int j = 0; j < AN; j++)
                acc[i][j] = __builtin_amdgcn_mfma_f32_16x16x32_bf16(af[i], bfr[j],
                                                                    acc[i][j], 0, 0, 0);
    }

#pragma unroll
    for (int i = 0; i < AM; i++) {
#pragma unroll
        for (int j = 0; j < AN; j++) {
            int col = tn + wn * (AN * 16) + j * 16 + l15;
            float bv = BIAS ? bias[col] : 0.0f;
#pragma unroll
            for (int r = 0; r < 4; r++) {
                int row = tm + wm * (AM * 16) + i * 16 + quad * 4 + r;
                float v = acc[i][j][r] + bv;
                if (RELU) v = fmaxf(v, 0.0f);
                if (OUTF32) ((float*)Cout)[(size_t)row * N + col] = v;
                else        ((u16*)Cout)[(size_t)row * N + col] = f2bf(v);
            }
        }
    }
}

// ---------------------------------------------------------------------------
// MFMA flash attention, software-pipelined K/V staging (double-buffered,
// one barrier per key-tile). Block = (b, h, 64-q tile); wave owns 16 q-rows.
// ---------------------------------------------------------------------------
__global__ __launch_bounds__(256) void flash_attn_mfma(const u16* __restrict__ QKV,
                                                       const u16* __restrict__ VT,
                                                       u16* __restrict__ O) {
    const int q0 = blockIdx.x * 64;
    const int h  = blockIdx.y;
    const int b  = blockIdx.z;
    const int tid  = threadIdx.x;
    const int wave = tid >> 6;
    const int lane = tid & 63;
    const int quad = lane >> 4;
    const int l15  = lane & 15;

    __shared__ u16 Ks[2][64 * 64];   // 2 x 8 KB
    __shared__ u16 Vs[2][128 * 64];  // 2 x 16 KB
    __shared__ u16 Pl[4][16 * 68];   // per-wave P; stride 68: quads at banks 0/8/16/24

    auto issueKV = [&](int kt, int buf) {
#pragma unroll
        for (int it = 0; it < 2; it++) {
            int cid = it * 256 + tid;
            int c = cid >> 8, p = cid & 255;
            async16(QKV + (size_t)(b * SLEN + kt + (p >> 2)) * 2048 + 512 + h * 64 +
                        c * 32 + (p & 3) * 8,
                    (char*)Ks[buf] + (it * 256 + wave * 64) * 16);
        }
#pragma unroll
        for (int it = 0; it < 4; it++) {
            int cid = it * 256 + tid;
            int c = cid >> 9, p = cid & 511;
            async16(VT + (size_t)((b * 8 + h) * 128 + (p >> 2)) * 2048 + kt +
                        c * 32 + (p & 3) * 8,
                    (char*)Vs[buf] + (it * 256 + wave * 64) * 16);
        }
    };

    bf16x8 qf[2];
    {
        const u16* p = QKV + (size_t)(b * SLEN + q0 + wave * 16 + l15) * 2048 +
                       h * 64 + quad * 8;
        qf[0] = *(const bf16x8*)p;
        qf[1] = *(const bf16x8*)(p + 32);
    }

    f32x4 o_acc[8];
#pragma unroll
    for (int t = 0; t < 8; t++) o_acc[t] = (f32x4){0.f, 0.f, 0.f, 0.f};
    float m_r[4] = {-1e30f, -1e30f, -1e30f, -1e30f};
    float l_r[4] = {0.f, 0.f, 0.f, 0.f};

    issueKV(0, 0);

    for (int ti = 0; ti < SLEN / 64; ti++) {
        __syncthreads();             // implicit vmcnt(0): loads(ti) landed
        if (ti + 1 < SLEN / 64) issueKV((ti + 1) * 64, (ti + 1) & 1);
        const int buf = ti & 1;

        // S = Q K^T  (rows quad*4+r, cols t*16+l15)
        f32x4 s_acc[4];
#pragma unroll
        for (int t = 0; t < 4; t++) s_acc[t] = (f32x4){0.f, 0.f, 0.f, 0.f};
#pragma unroll
        for (int c = 0; c < 2; c++)
#pragma unroll
            for (int t = 0; t < 4; t++) {
                bf16x8 kb = *(const bf16x8*)((const char*)Ks[buf] + c * 4096 +
                             ((t * 16 + l15) * 4 + quad) * 16);
                s_acc[t] = __builtin_amdgcn_mfma_f32_16x16x32_bf16(qf[c], kb,
                                                                   s_acc[t], 0, 0, 0);
            }

        // online softmax per q-row (replicated across the 16 lanes of each quad)
        float alpha[4];
#pragma unroll
        for (int r = 0; r < 4; r++) {
            float mx = fmaxf(fmaxf(s_acc[0][r], s_acc[1][r]),
                             fmaxf(s_acc[2][r], s_acc[3][r]));
#pragma unroll
            for (int off = 1; off < 16; off <<= 1) mx = fmaxf(mx, __shfl_xor(mx, off, 64));
            float mnew = fmaxf(m_r[r], mx);
            alpha[r] = __expf(m_r[r] - mnew);
            float ls = 0.f;
#pragma unroll
            for (int t = 0; t < 4; t++) {
                float pv = __expf(s_acc[t][r] - mnew);
                ls += pv;
                Pl[wave][(quad * 4 + r) * 68 + t * 16 + l15] = f2bf(pv);
            }
#pragma unroll
            for (int off = 1; off < 16; off <<= 1) ls += __shfl_xor(ls, off, 64);
            l_r[r] = l_r[r] * alpha[r] + ls;
            m_r[r] = mnew;
        }
#pragma unroll
        for (int t = 0; t < 8; t++)
#pragma unroll
            for (int r = 0; r < 4; r++) o_acc[t][r] *= alpha[r];

        __asm__ volatile("s_waitcnt lgkmcnt(0)" ::: "memory");  // P writes -> reads (wave-local)

        // O += P V
#pragma unroll
        for (int c = 0; c < 2; c++) {
            bf16x8 pf = *(const bf16x8*)((const char*)&Pl[wave][0] +
                         l15 * 136 + c * 64 + quad * 16);
#pragma unroll
            for (int t = 0; t < 8; t++) {
                bf16x8 vb = *(const bf16x8*)((const char*)Vs[buf] + c * 8192 +
                             ((t * 16 + l15) * 4 + quad) * 16);
                o_acc[t] = __builtin_amdgcn_mfma_f32_16x16x32_bf16(pf, vb,
                                                                   o_acc[t], 0, 0, 0);
            }
        }
    }

#pragma unroll
    for (int r = 0; r < 4; r++) {
        float inv = ATT_SCALING / l_r[r];
        size_t base = (size_t)(b * SLEN + q0 + wave * 16 + quad * 4 + r) * 1024 + h * 128;
#pragma unroll
        for (int t = 0; t < 8; t++)
            O[base + t * 16 + l15] = f2bf(o_acc[t][r] * inv);
    }
}

// ---------------------------------------------------------------------------
// LN(X + R) * g + be : fp32 in, fp32 + bf16 out (one block per 512-row)
// ---------------------------------------------------------------------------
__global__ __launch_bounds__(256) void addln_kernel(const float* __restrict__ X,
                                                    const float* __restrict__ R,
                                                    const float* __restrict__ g,
                                                    const float* __restrict__ be,
                                                    float* __restrict__ dstf,
                                                    u16* __restrict__ dstb) {
    const int row = blockIdx.x;
    const int tid = threadIdx.x;
    __shared__ float red[256];
    size_t off = (size_t)row * HIDDEN;
    float v0 = X[off + tid] + R[off + tid];
    float v1 = X[off + tid + 256] + R[off + tid + 256];
    red[tid] = v0 + v1;
    __syncthreads();
    for (int s = 128; s > 0; s >>= 1) { if (tid < s) red[tid] += red[tid + s]; __syncthreads(); }
    float mu = red[0] * (1.0f / HIDDEN);
    __syncthreads();
    float d0 = v0 - mu, d1 = v1 - mu;
    red[tid] = d0 * d0 + d1 * d1;
    __syncthreads();
    for (int s = 128; s > 0; s >>= 1) { if (tid < s) red[tid] += red[tid + s]; __syncthreads(); }
    float rstd = rsqrtf(red[0] * (1.0f / HIDDEN) + LN_EPS);
    float o0 = d0 * rstd * g[tid] + be[tid];
    float o1 = d1 * rstd * g[tid + 256] + be[tid + 256];
    dstf[off + tid] = o0;
    dstf[off + tid + 256] = o1;
    dstb[off + tid] = f2bf(o0);
    dstb[off + tid + 256] = f2bf(o1);
}

// ---------------------------------------------------------------------------
extern "C" void kernel_launch(void* const* d_in, const int* in_sizes, int n_in,
                              void* d_out, int out_size, void* d_ws, size_t ws_size,
                              hipStream_t stream) {
    const float* x   = (const float*)d_in[0];
    const float* Wq  = (const float*)d_in[1];
    const float* Wk  = (const float*)d_in[2];
    const float* Wv  = (const float*)d_in[3];
    const float* Wo  = (const float*)d_in[4];
    const float* W1  = (const float*)d_in[5];
    const float* b1  = (const float*)d_in[6];
    const float* W2  = (const float*)d_in[7];
    const float* b2  = (const float*)d_in[8];
    const float* g1  = (const float*)d_in[9];
    const float* be1 = (const float*)d_in[10];
    const float* g2  = (const float*)d_in[11];
    const float* be2 = (const float*)d_in[12];
    float* out = (float*)d_out;

    // Workspace (62.5 MB used):
    //  R1 [ 0..8M)  : A_f32 residual -> F2 fp32
    //  R2 [ 8..16M) : VT (attn)      -> Y_f32
    //  R3 [16..24M) : A_bf (4M)      -> P fp32 (8M)
    //  R4 [24..40M) : QKV bf16 (16M) -> F1 bf16
    //  R5 [40..48M) : AT bf16 (8M)   -> Y_bf (4M)
    //  R6 [48..62M) : bf16 transposed weights
    //  R7 [62..62.5M): xpos table
    const size_t MB = 1u << 20;
    char* w = (char*)d_ws;
    float*  R1f  = (float*)(w);
    u16*    VTg  = (u16*)(w + 8 * MB);
    float*  Yf   = (float*)(w + 8 * MB);
    u16*    A_bf = (u16*)(w + 16 * MB);
    float*  Pf   = (float*)(w + 16 * MB);
    u16*    QKV  = (u16*)(w + 24 * MB);
    u16*    F1   = (u16*)(w + 24 * MB);
    u16*    AT   = (u16*)(w + 40 * MB);
    u16*    Y_bf = (u16*)(w + 40 * MB);
    float2* xtab = (float2*)(w + 62 * MB);

    cvt_x<<<MROWS * HIDDEN / 256, 256, 0, stream>>>(x, R1f, A_bf);
    xpos_table<<<256, 256, 0, stream>>>(xtab);

    for (int l = 0; l < LAYERS; l++) {
        u16* WqkvT = (u16*)(w + 48 * MB + (size_t)l * 2 * MB);
        u16* WoT   = (u16*)(w + 52 * MB + (size_t)l * 1 * MB);
        u16* W1T   = (u16*)(w + 54 * MB + (size_t)l * 2 * MB);
        u16* W2T   = (u16*)(w + 58 * MB + (size_t)l * 2 * MB);
        wtrans<<<dim3(16, 16), 256, 0, stream>>>(Wq + (size_t)l * 512 * 512,  WqkvT,              512, 512);
        wtrans<<<dim3(16, 16), 256, 0, stream>>>(Wk + (size_t)l * 512 * 512,  WqkvT + 512 * 512,  512, 512);
        wtrans<<<dim3(32, 16), 256, 0, stream>>>(Wv + (size_t)l * 512 * 1024, WqkvT + 1024 * 512, 512, 1024);
        wtrans<<<dim3(16, 32), 256, 0, stream>>>(Wo + (size_t)l * 1024 * 512, WoT,                1024, 512);
        wtrans<<<dim3(64, 16), 256, 0, stream>>>(W1 + (size_t)l * 512 * 2048, W1T,                512, 2048);
        wtrans<<<dim3(16, 64), 256, 0, stream>>>(W2 + (size_t)l * 2048 * 512, W2T,                2048, 512);
    }

    for (int l = 0; l < LAYERS; l++) {
        u16* WqkvT = (u16*)(w + 48 * MB + (size_t)l * 2 * MB);
        u16* WoT   = (u16*)(w + 52 * MB + (size_t)l * 1 * MB);
        u16* W1T   = (u16*)(w + 54 * MB + (size_t)l * 2 * MB);
        u16* W2T   = (u16*)(w + 58 * MB + (size_t)l * 2 * MB);
        const float* b1_l  = b1 + (size_t)l * FFN_DIM;
        const float* b2_l  = b2 + (size_t)l * HIDDEN;
        const float* g1_l  = g1 + (size_t)l * HIDDEN;
        const float* be1_l = be1 + (size_t)l * HIDDEN;
        const float* g2_l  = g2 + (size_t)l * HIDDEN;
        const float* be2_l = be2 + (size_t)l * HIDDEN;

        // QKV = A_bf @ [Wq|Wk|Wv]  (bf16 out), 512 blocks
        gemm_mfma<128, 128, 2, 0, 0, 0><<<dim3(16, 32), 256, 0, stream>>>(
            A_bf, WqkvT, nullptr, QKV, MROWS, 2048, 512);

        xpos_kernel<<<4096, 256, 0, stream>>>(QKV, xtab);
        vtrans<<<dim3(32, 2, 16), 256, 0, stream>>>(QKV, VTg);

        flash_attn_mfma<<<dim3(32, 8, 2), 256, 0, stream>>>(QKV, VTg, AT);

        // P = AT @ Wo (fp32 out), 64x64 tiles -> 512 blocks
        gemm_mfma<64, 64, 2, 1, 0, 0><<<dim3(8, 64), 256, 0, stream>>>(
            AT, WoT, nullptr, Pf, MROWS, 512, 1024);

        // Y = LN(A + P)
        addln_kernel<<<MROWS, 256, 0, stream>>>(R1f, Pf, g1_l, be1_l, Yf, Y_bf);

        // F1 = relu(Y @ W1 + b1) (bf16 out), 512 blocks
        gemm_mfma<128, 128, 2, 0, 1, 1><<<dim3(16, 32), 256, 0, stream>>>(
            Y_bf, W1T, b1_l, F1, MROWS, 2048, 512);

        // F2 = F1 @ W2 + b2 (fp32 out), 64x64 tiles -> 512 blocks
        gemm_mfma<64, 64, 2, 1, 1, 0><<<dim3(8, 64), 256, 0, stream>>>(
            F1, W2T, b2_l, R1f, MROWS, 512, 2048);

        // x_next = LN(Y + F2)
        float* dstf = (l == LAYERS - 1) ? out : R1f;
        addln_kernel<<<MROWS, 256, 0, stream>>>(Yf, R1f, g2_l, be2_l, dstf, A_bf);
    }
}